// Round 1
// baseline (30.225 us; speedup 1.0000x reference)
//
#include <hip/hip_runtime.h>
#include <math.h>

#define NBLK 2048
#define NTHR 256

// Kernel 1: grid-stride float4 reduction producing per-block (sum, sumsq).
__global__ __launch_bounds__(NTHR) void grt_partial_kernel(
    const float* __restrict__ x, float2* __restrict__ part, int n4) {
    const float4* __restrict__ x4 = reinterpret_cast<const float4*>(x);
    int tid = blockIdx.x * blockDim.x + threadIdx.x;
    int stride = gridDim.x * blockDim.x;

    float s = 0.0f, q = 0.0f;
    for (int i = tid; i < n4; i += stride) {
        float4 v = x4[i];
        s += v.x + v.y + v.z + v.w;
        q = fmaf(v.x, v.x, q);
        q = fmaf(v.y, v.y, q);
        q = fmaf(v.z, v.z, q);
        q = fmaf(v.w, v.w, q);
    }

    // Wave (64-lane) shuffle reduction.
    #pragma unroll
    for (int off = 32; off > 0; off >>= 1) {
        s += __shfl_down(s, off, 64);
        q += __shfl_down(q, off, 64);
    }

    __shared__ float2 lds[NTHR / 64];
    int lane = threadIdx.x & 63;
    int wave = threadIdx.x >> 6;
    if (lane == 0) lds[wave] = make_float2(s, q);
    __syncthreads();

    if (threadIdx.x == 0) {
        float2 acc = lds[0];
        #pragma unroll
        for (int w = 1; w < NTHR / 64; ++w) {
            acc.x += lds[w].x;
            acc.y += lds[w].y;
        }
        part[blockIdx.x] = acc;
    }
}

// Kernel 2: reduce per-block partials, evaluate closed-form MVN log-prob.
__global__ __launch_bounds__(NTHR) void grt_final_kernel(
    const float2* __restrict__ part, int npart,
    const float* __restrict__ log_sw, const float* __restrict__ log_sz,
    const float* __restrict__ log_sx, float* __restrict__ out, float dn) {
    float s = 0.0f, q = 0.0f;
    for (int i = threadIdx.x; i < npart; i += NTHR) {
        float2 v = part[i];
        s += v.x;
        q += v.y;
    }

    #pragma unroll
    for (int off = 32; off > 0; off >>= 1) {
        s += __shfl_down(s, off, 64);
        q += __shfl_down(q, off, 64);
    }

    __shared__ float2 lds[NTHR / 64];
    int lane = threadIdx.x & 63;
    int wave = threadIdx.x >> 6;
    if (lane == 0) lds[wave] = make_float2(s, q);
    __syncthreads();

    if (threadIdx.x == 0) {
        double ss = 0.0, qq = 0.0;
        #pragma unroll
        for (int w = 0; w < NTHR / 64; ++w) {
            ss += (double)lds[w].x;
            qq += (double)lds[w].y;
        }
        double n = (double)dn;
        double b = exp(2.0 * (double)log_sw[0]);
        double a = exp(2.0 * (double)log_sz[0]) + exp(2.0 * (double)log_sx[0]);
        double quad = qq / a - b * ss * ss / (a * (a + n * b));
        double logdet = (n - 1.0) * log(a) + log(a + n * b);
        const double LOG_2PI = 1.837877066409345483560659472811;
        out[0] = (float)(-0.5 * (n * LOG_2PI + logdet + quad));
    }
}

extern "C" void kernel_launch(void* const* d_in, const int* in_sizes, int n_in,
                              void* d_out, int out_size, void* d_ws, size_t ws_size,
                              hipStream_t stream) {
    const float* x      = (const float*)d_in[0];
    const float* log_sw = (const float*)d_in[1];
    const float* log_sz = (const float*)d_in[2];
    const float* log_sx = (const float*)d_in[3];
    float* out = (float*)d_out;
    int n = in_sizes[0];           // 33554432
    int n4 = n >> 2;               // exactly divisible (2^25 / 4)

    float2* part = (float2*)d_ws;  // NBLK float2 = 16 KiB, well within ws

    grt_partial_kernel<<<NBLK, NTHR, 0, stream>>>(x, part, n4);
    grt_final_kernel<<<1, NTHR, 0, stream>>>(part, NBLK, log_sw, log_sz, log_sx,
                                             out, (float)n);
}